// Round 12
// baseline (2139.998 us; speedup 1.0000x reference)
//
#include <hip/hip_runtime.h>
#include <hip/hip_bf16.h>

#define B_  32
#define A_  128
#define T_  64
#define N_  4096        // B_*A_
#define HS  256
#define ES  32
#define RS  64
#define KX  832         // 64 (r) + 512 (e) + 256 (h)
#define GD  1024        // 4*HS
#define NKT 26          // KX/32

typedef __attribute__((ext_vector_type(8))) short bf8_t;            // 8 x bf16
typedef __attribute__((ext_vector_type(8))) unsigned short u16x8;
typedef __attribute__((ext_vector_type(4))) float f4_t;             // mfma acc
typedef __attribute__((ext_vector_type(2))) float f2_t;

__device__ __forceinline__ unsigned short f2bf(float x) {
  union { float f; unsigned u; } v; v.f = x;
  unsigned u = v.u;
  u += 0x7fffu + ((u >> 16) & 1u);     // round-to-nearest-even
  return (unsigned short)(u >> 16);
}
__device__ __forceinline__ float bf2f(unsigned short u) {
  union { unsigned u; float f; } v; v.u = ((unsigned)u) << 16; return v.f;
}
__device__ __forceinline__ float sigm(float x) { return 1.f / (1.f + __expf(-x)); }

__device__ __forceinline__ void gload16(const void* g, void* l) {
  __builtin_amdgcn_global_load_lds((const __attribute__((address_space(1))) void*)g,
                                   (__attribute__((address_space(3))) void*)l, 16, 0, 0);
}

// ---- Wc (permuted) + fused bias + bf16 W_e copy
__global__ void k_wcat(const float* __restrict__ W_ih, const float* __restrict__ W_hh,
                       const float* __restrict__ b_ih, const float* __restrict__ b_hh,
                       const float* __restrict__ W_e,
                       unsigned short* __restrict__ Wc, float* __restrict__ bsum,
                       unsigned short* __restrict__ Web) {
  int i = blockIdx.x * 256 + threadIdx.x;
  if (i < GD * KX) {
    int mp = i / KX, k = i - mp * KX;
    int nb = mp >> 6, rem = mp & 63, g = rem >> 4, q = rem & 15;
    int mo = g * 256 + nb * 16 + q;
    float v = (k < 576) ? W_ih[mo * 576 + k] : W_hh[mo * 256 + (k - 576)];
    Wc[i] = f2bf(v);
  } else if (i < GD * KX + GD) {
    int j = i - GD * KX;
    int nb = j >> 6, rem = j & 63, g = rem >> 4, q = rem & 15;
    int mo = g * 256 + nb * 16 + q;
    bsum[j] = b_ih[mo] + b_hh[mo];
  } else if (i < GD * KX + GD + ES * HS) {
    int j2 = i - GD * KX - GD;
    Web[j2] = f2bf(W_e[j2]);
  }
}

// ---- collapsed head: Whead[o][320] = (Wo @ W_p2) @ W_p   (5 blocks x 320 thr)
__global__ __launch_bounds__(320) void k_head(
    const float* __restrict__ W_p, const float* __restrict__ b_p,
    const float* __restrict__ W_p2, const float* __restrict__ b_p2,
    const float* __restrict__ W_mu, const float* __restrict__ b_mu,
    const float* __restrict__ W_sd, const float* __restrict__ b_sd,
    const float* __restrict__ W_cr, const float* __restrict__ b_cr,
    float* __restrict__ Whead, float* __restrict__ bhead) {
  int o = blockIdx.x, tid = threadIdx.x;
  __shared__ float to[64];
  const float* Wo = (o < 2) ? W_mu + o * 32 : (o < 4) ? W_sd + (o - 2) * 32 : W_cr;
  if (tid < 64) {
    float a = 0.f;
    #pragma unroll 8
    for (int c = 0; c < 32; ++c) a += Wo[c] * W_p2[c * 64 + tid];
    to[tid] = a;
  }
  __syncthreads();
  float a = 0.f;
  #pragma unroll 8
  for (int j = 0; j < 64; ++j) a += to[j] * W_p[j * 320 + tid];
  Whead[o * 320 + tid] = a;
  if (tid == 0) {
    float b0 = (o < 2) ? b_mu[o] : (o < 4) ? b_sd[o - 2] : b_cr[0];
    float acc = b0;
    for (int c = 0; c < 32; ++c) acc += Wo[c] * b_p2[c];
    for (int j = 0; j < 64; ++j) acc += to[j] * b_p[j];
    bhead[o] = acc;
  }
}

// ---- head for step ts, rows n0..n0+(threads/32). h2(ts) = bf16 h-part of Xh.
__device__ __forceinline__ void head_fin_dev(
    const float* __restrict__ data, const float* __restrict__ W_r,
    const float* __restrict__ b_r, const float* __restrict__ Whead,
    const float* __restrict__ bhead, const unsigned short* __restrict__ Xh,
    float* __restrict__ out, int n0, int ts, int tid) {
  int r8 = tid >> 5, ln = tid & 31;
  int n = n0 + r8;
  float s0 = 0.f, s1 = 0.f, s2 = 0.f, s3 = 0.f, s4 = 0.f;
  u16x8 hv = *(const u16x8*)(Xh + (size_t)n * KX + 576 + ln * 8);
  float hf[8];
  #pragma unroll
  for (int k = 0; k < 8; ++k) hf[k] = bf2f(hv[k]);
  #pragma unroll
  for (int k = 0; k < 8; ++k) {
    int kk = 64 + ln * 8 + k;
    s0 += hf[k] * Whead[0 * 320 + kk];
    s1 += hf[k] * Whead[1 * 320 + kk];
    s2 += hf[k] * Whead[2 * 320 + kk];
    s3 += hf[k] * Whead[3 * 320 + kk];
    s4 += hf[k] * Whead[4 * 320 + kk];
  }
  float x0 = data[(n * T_ + ts) * 2 + 0];
  float x1 = data[(n * T_ + ts) * 2 + 1];
  #pragma unroll
  for (int l2 = 0; l2 < 2; ++l2) {
    int l = ln + 32 * l2;
    float rv = fmaxf(x0 * W_r[l * 2] + x1 * W_r[l * 2 + 1] + b_r[l], 0.f);
    s0 += rv * Whead[0 * 320 + l];
    s1 += rv * Whead[1 * 320 + l];
    s2 += rv * Whead[2 * 320 + l];
    s3 += rv * Whead[3 * 320 + l];
    s4 += rv * Whead[4 * 320 + l];
  }
  #pragma unroll
  for (int off = 16; off; off >>= 1) {
    s0 += __shfl_xor(s0, off);
    s1 += __shfl_xor(s1, off);
    s2 += __shfl_xor(s2, off);
    s3 += __shfl_xor(s3, off);
    s4 += __shfl_xor(s4, off);
  }
  if (ln == 0) {
    out[(n * T_ + ts) * 2 + 0] = s0 + bhead[0];
    out[(n * T_ + ts) * 2 + 1] = s1 + bhead[1];
    out[N_ * T_ * 2 + (n * T_ + ts) * 2 + 0] = __expf(s2 + bhead[2]);
    out[N_ * T_ * 2 + (n * T_ + ts) * 2 + 1] = __expf(s3 + bhead[3]);
    out[N_ * T_ * 4 + n * T_ + ts] = tanhf(s4 + bhead[4]);
  }
}

// ---- social (256 blocks x 512 thr; block = (b, ig8) owning 16 rows)
__global__ __launch_bounds__(512) void k_social(
    const float* __restrict__ data, const unsigned short* __restrict__ Web,
    const float* __restrict__ b_e, unsigned short* __restrict__ Xcur,
    const float* __restrict__ Whead, const float* __restrict__ bhead,
    const float* __restrict__ W_r, const float* __restrict__ b_r,
    float* __restrict__ out, int t) {
  int b   = blockIdx.x >> 3;
  int ig8 = blockIdx.x & 7;
  int n0  = b * A_ + ig8 * 16;
  __shared__ float sx[A_], sy[A_];
  __shared__ float shw2[64 * 64];       // [jp][c][sub]  16 KB
  __shared__ float smx[16][64][8];      // 32 KB
  __shared__ float smy[16][64][8];      // 32 KB
  int tid = threadIdx.x;
  if (tid < A_) {
    sx[tid] = data[((b * A_ + tid) * T_ + t) * 2 + 0];
    sy[tid] = data[((b * A_ + tid) * T_ + t) * 2 + 1];
  }
  if (t > 0)
    head_fin_dev(data, W_r, b_r, Whead, bhead, Xcur, out, n0, t - 1, tid);
  for (int u = tid; u < 1024; u += 512) {
    int rr = u >> 6, l = u & 63;
    int n = n0 + rr;
    float x0 = data[(n * T_ + t) * 2 + 0];
    float x1 = data[(n * T_ + t) * 2 + 1];
    Xcur[(size_t)n * KX + l] =
        f2bf(fmaxf(x0 * W_r[l * 2] + x1 * W_r[l * 2 + 1] + b_r[l], 0.f));
  }
  if (t == 0) {
    for (int i = tid; i < 64 * 64; i += 512) shw2[i] = 0.f;
    u16x8 z = (u16x8){0, 0, 0, 0, 0, 0, 0, 0};
    int row = tid >> 5, c8 = tid & 31;
    *(u16x8*)(Xcur + (size_t)(n0 + row) * KX + 576 + c8 * 8) = z;
  } else {
    int w = tid >> 6, lane = tid & 63;
    int lr = lane & 15, lh = lane >> 4;
    const unsigned short* a0p = Xcur + (size_t)(b * A_ + w * 16 + lr) * KX + 576 + lh * 8;
    const unsigned short* b0p = Web + lr * HS + lh * 8;
    const unsigned short* b1p = Web + (16 + lr) * HS + lh * 8;
    f4_t hacc[2];
    hacc[0] = (f4_t){0.f, 0.f, 0.f, 0.f}; hacc[1] = hacc[0];
    #pragma unroll
    for (int kk = 0; kk < 8; ++kk) {
      bf8_t av  = *(const bf8_t*)(a0p + kk * 32);
      bf8_t bv0 = *(const bf8_t*)(b0p + kk * 32);
      bf8_t bv1 = *(const bf8_t*)(b1p + kk * 32);
      hacc[0] = __builtin_amdgcn_mfma_f32_16x16x32_bf16(av, bv0, hacc[0], 0, 0, 0);
      hacc[1] = __builtin_amdgcn_mfma_f32_16x16x32_bf16(av, bv1, hacc[1], 0, 0, 0);
    }
    int ccol = lane & 15, crow4 = (lane >> 4) * 4;
    #pragma unroll
    for (int cb2 = 0; cb2 < 2; ++cb2)
      #pragma unroll
      for (int j = 0; j < 4; ++j) {
        int rr = w * 16 + crow4 + j;
        int c  = cb2 * 16 + ccol;
        shw2[(rr >> 1) * 64 + c * 2 + (rr & 1)] = hacc[cb2][j];
      }
  }
  __syncthreads();

  for (int u = tid; u < 1024; u += 512) {
    int r = u >> 6, jp = u & 63;
    int irow = ig8 * 16 + r;
    float xi = sx[irow], yi = sy[irow];
    bool acti = xi >= 0.f;
    float m0[4], m1[4], nn0[4], nn1[4];
    #pragma unroll
    for (int s = 0; s < 2; ++s) {
      int j = jp * 2 + s;
      float xj = sx[j], yj = sy[j];
      bool v = acti && (xj >= 0.f) && (j != irow);
      float dx = xi - xj, dy = yi - yj;
      float* mm = s ? m1 : m0;
      float* nn = s ? nn1 : nn0;
      mm[0] = (v && dx >= 8.f   && dx <= 16.f) ? 1.f : 0.f;
      mm[1] = (v && dx >= 0.f   && dx <= 8.f ) ? 1.f : 0.f;
      mm[2] = (v && dx >= -8.f  && dx <= 0.f ) ? 1.f : 0.f;
      mm[3] = (v && dx >= -16.f && dx <= -8.f) ? 1.f : 0.f;
      nn[0] = (dy >= -16.f && dy <= -8.f) ? 1.f : 0.f;
      nn[1] = (dy >= -8.f  && dy <= 0.f ) ? 1.f : 0.f;
      nn[2] = (dy >= 0.f   && dy <= 8.f ) ? 1.f : 0.f;
      nn[3] = (dy >= 8.f   && dy <= 16.f) ? 1.f : 0.f;
    }
    float4* px = (float4*)&smx[r][jp][0];
    px[0] = (float4){m0[0], m1[0], m0[1], m1[1]};
    px[1] = (float4){m0[2], m1[2], m0[3], m1[3]};
    float4* py = (float4*)&smy[r][jp][0];
    py[0] = (float4){nn0[0], nn1[0], nn0[1], nn1[1]};
    py[1] = (float4){nn0[2], nn1[2], nn0[3], nn1[3]};
  }
  __syncthreads();

  int half = tid >> 5;               // row 0..15
  int lane = tid & 31;               // channel
  f2_t acc[16];
  #pragma unroll
  for (int g = 0; g < 16; ++g) acc[g] = (f2_t){0.f, 0.f};
  #pragma unroll 2
  for (int jp = 0; jp < 64; ++jp) {
    f2_t hv = *(const f2_t*)&shw2[jp * 64 + lane * 2];
    float4 xa = ((const float4*)&smx[half][jp][0])[0];
    float4 xb = ((const float4*)&smx[half][jp][0])[1];
    float4 ya = ((const float4*)&smy[half][jp][0])[0];
    float4 yb = ((const float4*)&smy[half][jp][0])[1];
    f2_t mx[4] = {(f2_t){xa.x, xa.y}, (f2_t){xa.z, xa.w},
                  (f2_t){xb.x, xb.y}, (f2_t){xb.z, xb.w}};
    f2_t p[4]  = {(f2_t){ya.x, ya.y} * hv, (f2_t){ya.z, ya.w} * hv,
                  (f2_t){yb.x, yb.y} * hv, (f2_t){yb.z, yb.w} * hv};
    #pragma unroll
    for (int gy = 0; gy < 4; ++gy)
      #pragma unroll
      for (int gx = 0; gx < 4; ++gx)
        acc[gy * 4 + gx] += mx[gx] * p[gy];
  }

  int irow = ig8 * 16 + half;
  float be = b_e[lane];
  int hi = irow >> 4;                // == ig8
  int klo = (irow & 15) * ES + lane;
  #pragma unroll
  for (int g = 0; g < 16; ++g) {
    float e = fmaxf(acc[g][0] + acc[g][1] + be, 0.f);
    int a_out = g * 8 + hi;
    Xcur[(size_t)(b * A_ + a_out) * KX + 64 + klo] = f2bf(e);
  }
}

// ---- gates GEMM + register-direct LSTM pointwise.
// BM=128, BN=64, BK=32, 256 thr, grid 512 (2 blocks/CU for latency hiding).
// 4 waves x (32 rows x 64 cols) so each lane holds all 4 gates of its channel.
// 4-buffer rotation, counted vmcnt(2), raw s_barrier.
__global__ __launch_bounds__(256) void k_gemm_lstm(
    const unsigned short* __restrict__ Xcur, const unsigned short* __restrict__ Wc,
    const float* __restrict__ bsum,
    float* __restrict__ cbuf, unsigned short* __restrict__ Xnext, int t) {
  __shared__ unsigned short sA0[128 * 32], sB0[64 * 32];   // 8 KB + 4 KB
  __shared__ unsigned short sA1[128 * 32], sB1[64 * 32];
  __shared__ unsigned short sA2[128 * 32], sB2[64 * 32];
  __shared__ unsigned short sA3[128 * 32], sB3[64 * 32];   // total 48 KB

  int bid = blockIdx.x;
  int tm = bid & 31, tc = bid >> 5;          // 32 batches x 16 col-tiles
  int row0 = tm * 128, col0 = tc * 64;
  int tid = threadIdx.x;
  int lane = tid & 63;
  int w = tid >> 6;                          // 4 waves: 32-row strips
  int lr = lane & 15, lh = lane >> 4;

  // staging: A rows tid>>2 (0..63 => two gloads), B rows tid>>2 (0..63)
  int srow = tid >> 2, schunk = tid & 3;
  int gch = (schunk ^ ((srow >> 1) & 3)) * 8;
  const unsigned short* gA = Xcur + (size_t)(row0 + srow) * KX + gch;
  const unsigned short* gB = Wc  + (size_t)(col0 + srow) * KX + gch;
  // A rows 64..127: srow+64 -> (srow+64)>>1 = srow>>1 + 32 == same swizzle mod 4

  int swz = (lh ^ ((lr >> 1) & 3)) * 8;
  int aoff[2], boff[4];
  #pragma unroll
  for (int m = 0; m < 2; ++m) aoff[m] = (w * 32 + m * 16 + lr) * 32 + swz;
  #pragma unroll
  for (int n = 0; n < 4; ++n) boff[n] = (n * 16 + lr) * 32 + swz;

  f4_t acc[2][4];
  #pragma unroll
  for (int m = 0; m < 2; ++m)
    #pragma unroll
    for (int n = 0; n < 4; ++n) acc[m][n] = (f4_t){0.f, 0.f, 0.f, 0.f};

#define STAGE(pA, pB, kt) do { \
    gload16(gA + (size_t)(kt) * 32, (pA) + tid * 8); \
    gload16(gA + (size_t)64 * KX + (kt) * 32, (pA) + 2048 + tid * 8); \
    gload16(gB + (size_t)(kt) * 32, (pB) + tid * 8); \
  } while (0)

#define COMPUTE(pA, pB) do { \
    bf8_t a_[2], b_[4]; \
    _Pragma("unroll") for (int m = 0; m < 2; ++m) a_[m] = *(const bf8_t*)((pA) + aoff[m]); \
    _Pragma("unroll") for (int n = 0; n < 4; ++n) b_[n] = *(const bf8_t*)((pB) + boff[n]); \
    _Pragma("unroll") for (int m = 0; m < 2; ++m) \
      _Pragma("unroll") for (int n = 0; n < 4; ++n) \
        acc[m][n] = __builtin_amdgcn_mfma_f32_16x16x32_bf16(a_[m], b_[n], acc[m][n], 0, 0, 0); \
  } while (0)

// stage kt ready (vmcnt(3): kt+1's 3 loads stay in flight), prefetch kt+2,
// compute kt. 3 loads/stage -> outstanding after prologue = 6.
#define ITER(AC, BC, AN, BN, kt) do { \
    asm volatile("s_waitcnt vmcnt(3)" ::: "memory"); \
    __builtin_amdgcn_sched_barrier(0); \
    __builtin_amdgcn_s_barrier(); \
    STAGE(AN, BN, (kt) + 2); \
    COMPUTE(AC, BC); \
  } while (0)

  STAGE(sA0, sB0, 0);
  STAGE(sA1, sB1, 1);
  #pragma unroll 1
  for (int kt = 0; kt < 24; kt += 4) {
    ITER(sA0, sB0, sA2, sB2, kt);
    ITER(sA1, sB1, sA3, sB3, kt + 1);
    ITER(sA2, sB2, sA0, sB0, kt + 2);
    ITER(sA3, sB3, sA1, sB1, kt + 3);
  }
  // kt = 24: ready when only stage-25's 3 loads remain
  asm volatile("s_waitcnt vmcnt(3)" ::: "memory");
  __builtin_amdgcn_sched_barrier(0);
  __builtin_amdgcn_s_barrier();
  COMPUTE(sA0, sB0);
  // kt = 25: drain fully
  asm volatile("s_waitcnt vmcnt(0)" ::: "memory");
  __builtin_amdgcn_sched_barrier(0);
  __builtin_amdgcn_s_barrier();
  COMPUTE(sA1, sB1);
#undef ITER
#undef STAGE
#undef COMPUTE

  // register-direct LSTM pointwise
  int q = lane & 15;
  float bias_g[4];
  #pragma unroll
  for (int n = 0; n < 4; ++n) bias_g[n] = bsum[col0 + n * 16 + q];
  int ch = tc * 16 + q;
  int jrow4 = (lane >> 4) * 4;
  #pragma unroll
  for (int m = 0; m < 2; ++m) {
    #pragma unroll
    for (int j = 0; j < 4; ++j) {
      int row = row0 + w * 32 + m * 16 + jrow4 + j;
      float ig = acc[m][0][j] + bias_g[0];
      float fg = acc[m][1][j] + bias_g[1];
      float gg = acc[m][2][j] + bias_g[2];
      float og = acc[m][3][j] + bias_g[3];
      float cold = (t == 0) ? 0.f : cbuf[(size_t)row * HS + ch];
      float c2 = sigm(fg) * cold + sigm(ig) * tanhf(gg);
      float h2 = sigm(og) * tanhf(c2);
      cbuf[(size_t)row * HS + ch] = c2;
      Xnext[(size_t)row * KX + 576 + ch] = f2bf(h2);
    }
  }
}

// ---- final head for t=63 (512 blocks x 8 rows); Xh = X holding h2(63)
__global__ __launch_bounds__(256) void k_fin(
    const float* __restrict__ data, const float* __restrict__ W_r,
    const float* __restrict__ b_r, const float* __restrict__ Whead,
    const float* __restrict__ bhead, const unsigned short* __restrict__ Xh,
    float* __restrict__ out) {
  head_fin_dev(data, W_r, b_r, Whead, bhead, Xh, out,
               blockIdx.x * 8, T_ - 1, threadIdx.x);
}

extern "C" void kernel_launch(void* const* d_in, const int* in_sizes, int n_in,
                              void* d_out, int out_size, void* d_ws, size_t ws_size,
                              hipStream_t stream) {
  const float* data = (const float*)d_in[0];
  const float* W_r  = (const float*)d_in[2];
  const float* b_r  = (const float*)d_in[3];
  const float* W_e  = (const float*)d_in[4];
  const float* b_e  = (const float*)d_in[5];
  const float* W_ih = (const float*)d_in[6];
  const float* W_hh = (const float*)d_in[7];
  const float* b_ih = (const float*)d_in[8];
  const float* b_hh = (const float*)d_in[9];
  const float* W_p  = (const float*)d_in[10];
  const float* b_p  = (const float*)d_in[11];
  const float* W_p2 = (const float*)d_in[12];
  const float* b_p2 = (const float*)d_in[13];
  const float* W_mu = (const float*)d_in[14];
  const float* b_mu = (const float*)d_in[15];
  const float* W_sd = (const float*)d_in[16];
  const float* b_sd = (const float*)d_in[17];
  const float* W_cr = (const float*)d_in[18];
  const float* b_cr = (const float*)d_in[19];
  float* out = (float*)d_out;

  char* ws = (char*)d_ws;
  float* cbuf  = (float*)(ws);                                // 4 MB
  unsigned short* Xbf0 = (unsigned short*)(ws + (4u  << 20)); // 6.5 MB
  unsigned short* Xbf1 = (unsigned short*)(ws + (11u << 20)); // 6.5 MB
  unsigned short* Wc   = (unsigned short*)(ws + (18u << 20)); // 1.7 MB
  float* bsum  = (float*)(ws + (20u << 20));                  // 4 KB
  float* Whead = (float*)(ws + (20u << 20) + 8192);           // 6.4 KB
  float* bhead = (float*)(ws + (20u << 20) + 16384);          // 20 B
  unsigned short* Web = (unsigned short*)(ws + (20u << 20) + 20480); // 16 KB

  k_wcat<<<(GD * KX + GD + ES * HS + 255) / 256, 256, 0, stream>>>(
      W_ih, W_hh, b_ih, b_hh, W_e, Wc, bsum, Web);
  k_head<<<5, 320, 0, stream>>>(W_p, b_p, W_p2, b_p2, W_mu, b_mu, W_sd, b_sd, W_cr, b_cr,
                                Whead, bhead);

  for (int t = 0; t < T_; ++t) {
    unsigned short* Xcur  = (t & 1) ? Xbf1 : Xbf0;
    unsigned short* Xnext = (t & 1) ? Xbf0 : Xbf1;
    k_social<<<256, 512, 0, stream>>>(data, Web, b_e, Xcur, Whead, bhead,
                                      W_r, b_r, out, t);
    k_gemm_lstm<<<512, 256, 0, stream>>>(Xcur, Wc, bsum, cbuf, Xnext, t);
  }
  // h2(63) lives in Xnext of t=63 -> Xbf0 (t=63 odd)
  k_fin<<<512, 256, 0, stream>>>(data, W_r, b_r, Whead, bhead, Xbf0, out);
}

// Round 13
// 1990.948 us; speedup vs baseline: 1.0749x; 1.0749x over previous
//
#include <hip/hip_runtime.h>
#include <hip/hip_bf16.h>

#define B_  32
#define A_  128
#define T_  64
#define N_  4096        // B_*A_
#define HS  256
#define ES  32
#define RS  64
#define KX  832         // 64 (r) + 512 (e) + 256 (h)
#define GD  1024        // 4*HS
#define NKT 26          // KX/32

typedef __attribute__((ext_vector_type(8))) short bf8_t;            // 8 x bf16
typedef __attribute__((ext_vector_type(8))) unsigned short u16x8;
typedef __attribute__((ext_vector_type(4))) float f4_t;             // mfma acc
typedef __attribute__((ext_vector_type(2))) float f2_t;

__device__ __forceinline__ unsigned short f2bf(float x) {
  union { float f; unsigned u; } v; v.f = x;
  unsigned u = v.u;
  u += 0x7fffu + ((u >> 16) & 1u);     // round-to-nearest-even
  return (unsigned short)(u >> 16);
}
__device__ __forceinline__ float bf2f(unsigned short u) {
  union { unsigned u; float f; } v; v.u = ((unsigned)u) << 16; return v.f;
}
__device__ __forceinline__ float sigm(float x) { return 1.f / (1.f + __expf(-x)); }

__device__ __forceinline__ void gload16(const void* g, void* l) {
  __builtin_amdgcn_global_load_lds((const __attribute__((address_space(1))) void*)g,
                                   (__attribute__((address_space(3))) void*)l, 16, 0, 0);
}

// ---- Wc (permuted) + fused bias + bf16 W_e copy
__global__ void k_wcat(const float* __restrict__ W_ih, const float* __restrict__ W_hh,
                       const float* __restrict__ b_ih, const float* __restrict__ b_hh,
                       const float* __restrict__ W_e,
                       unsigned short* __restrict__ Wc, float* __restrict__ bsum,
                       unsigned short* __restrict__ Web) {
  int i = blockIdx.x * 256 + threadIdx.x;
  if (i < GD * KX) {
    int mp = i / KX, k = i - mp * KX;
    int nb = mp >> 6, rem = mp & 63, g = rem >> 4, q = rem & 15;
    int mo = g * 256 + nb * 16 + q;
    float v = (k < 576) ? W_ih[mo * 576 + k] : W_hh[mo * 256 + (k - 576)];
    Wc[i] = f2bf(v);
  } else if (i < GD * KX + GD) {
    int j = i - GD * KX;
    int nb = j >> 6, rem = j & 63, g = rem >> 4, q = rem & 15;
    int mo = g * 256 + nb * 16 + q;
    bsum[j] = b_ih[mo] + b_hh[mo];
  } else if (i < GD * KX + GD + ES * HS) {
    int j2 = i - GD * KX - GD;
    Web[j2] = f2bf(W_e[j2]);
  }
}

// ---- collapsed head: Whead[o][320] = (Wo @ W_p2) @ W_p   (5 blocks x 320 thr)
__global__ __launch_bounds__(320) void k_head(
    const float* __restrict__ W_p, const float* __restrict__ b_p,
    const float* __restrict__ W_p2, const float* __restrict__ b_p2,
    const float* __restrict__ W_mu, const float* __restrict__ b_mu,
    const float* __restrict__ W_sd, const float* __restrict__ b_sd,
    const float* __restrict__ W_cr, const float* __restrict__ b_cr,
    float* __restrict__ Whead, float* __restrict__ bhead) {
  int o = blockIdx.x, tid = threadIdx.x;
  __shared__ float to[64];
  const float* Wo = (o < 2) ? W_mu + o * 32 : (o < 4) ? W_sd + (o - 2) * 32 : W_cr;
  if (tid < 64) {
    float a = 0.f;
    #pragma unroll 8
    for (int c = 0; c < 32; ++c) a += Wo[c] * W_p2[c * 64 + tid];
    to[tid] = a;
  }
  __syncthreads();
  float a = 0.f;
  #pragma unroll 8
  for (int j = 0; j < 64; ++j) a += to[j] * W_p[j * 320 + tid];
  Whead[o * 320 + tid] = a;
  if (tid == 0) {
    float b0 = (o < 2) ? b_mu[o] : (o < 4) ? b_sd[o - 2] : b_cr[0];
    float acc = b0;
    for (int c = 0; c < 32; ++c) acc += Wo[c] * b_p2[c];
    for (int j = 0; j < 64; ++j) acc += to[j] * b_p[j];
    bhead[o] = acc;
  }
}

// ---- head for step ts, rows n0..n0+(threads/32). h2(ts) = bf16 h-part of Xh.
__device__ __forceinline__ void head_fin_dev(
    const float* __restrict__ data, const float* __restrict__ W_r,
    const float* __restrict__ b_r, const float* __restrict__ Whead,
    const float* __restrict__ bhead, const unsigned short* __restrict__ Xh,
    float* __restrict__ out, int n0, int ts, int tid) {
  int r8 = tid >> 5, ln = tid & 31;
  int n = n0 + r8;
  float s0 = 0.f, s1 = 0.f, s2 = 0.f, s3 = 0.f, s4 = 0.f;
  u16x8 hv = *(const u16x8*)(Xh + (size_t)n * KX + 576 + ln * 8);
  float hf[8];
  #pragma unroll
  for (int k = 0; k < 8; ++k) hf[k] = bf2f(hv[k]);
  #pragma unroll
  for (int k = 0; k < 8; ++k) {
    int kk = 64 + ln * 8 + k;
    s0 += hf[k] * Whead[0 * 320 + kk];
    s1 += hf[k] * Whead[1 * 320 + kk];
    s2 += hf[k] * Whead[2 * 320 + kk];
    s3 += hf[k] * Whead[3 * 320 + kk];
    s4 += hf[k] * Whead[4 * 320 + kk];
  }
  float x0 = data[(n * T_ + ts) * 2 + 0];
  float x1 = data[(n * T_ + ts) * 2 + 1];
  #pragma unroll
  for (int l2 = 0; l2 < 2; ++l2) {
    int l = ln + 32 * l2;
    float rv = fmaxf(x0 * W_r[l * 2] + x1 * W_r[l * 2 + 1] + b_r[l], 0.f);
    s0 += rv * Whead[0 * 320 + l];
    s1 += rv * Whead[1 * 320 + l];
    s2 += rv * Whead[2 * 320 + l];
    s3 += rv * Whead[3 * 320 + l];
    s4 += rv * Whead[4 * 320 + l];
  }
  #pragma unroll
  for (int off = 16; off; off >>= 1) {
    s0 += __shfl_xor(s0, off);
    s1 += __shfl_xor(s1, off);
    s2 += __shfl_xor(s2, off);
    s3 += __shfl_xor(s3, off);
    s4 += __shfl_xor(s4, off);
  }
  if (ln == 0) {
    out[(n * T_ + ts) * 2 + 0] = s0 + bhead[0];
    out[(n * T_ + ts) * 2 + 1] = s1 + bhead[1];
    out[N_ * T_ * 2 + (n * T_ + ts) * 2 + 0] = __expf(s2 + bhead[2]);
    out[N_ * T_ * 2 + (n * T_ + ts) * 2 + 1] = __expf(s3 + bhead[3]);
    out[N_ * T_ * 4 + n * T_ + ts] = tanhf(s4 + bhead[4]);
  }
}

// ---- social (256 blocks x 512 thr; block = (b, ig8) owning 16 rows)
// XCD-aligned mapping: b = bid&31 so XCD(bid)=bid%8=b%8 — matches gemm's
// tm=bid&31 mapping; batch dataflow (X, cbuf, h2) stays in one XCD L2.
__global__ __launch_bounds__(512) void k_social(
    const float* __restrict__ data, const unsigned short* __restrict__ Web,
    const float* __restrict__ b_e, unsigned short* __restrict__ Xcur,
    const float* __restrict__ Whead, const float* __restrict__ bhead,
    const float* __restrict__ W_r, const float* __restrict__ b_r,
    float* __restrict__ out, int t) {
  int b   = blockIdx.x & 31;
  int ig8 = blockIdx.x >> 5;
  int n0  = b * A_ + ig8 * 16;
  __shared__ float sx[A_], sy[A_];
  __shared__ float shw2[64 * 64];       // [jp][c][sub]  16 KB
  __shared__ float smx[16][64][8];      // 32 KB
  __shared__ float smy[16][64][8];      // 32 KB
  int tid = threadIdx.x;
  if (tid < A_) {
    sx[tid] = data[((b * A_ + tid) * T_ + t) * 2 + 0];
    sy[tid] = data[((b * A_ + tid) * T_ + t) * 2 + 1];
  }
  if (t > 0)
    head_fin_dev(data, W_r, b_r, Whead, bhead, Xcur, out, n0, t - 1, tid);
  for (int u = tid; u < 1024; u += 512) {
    int rr = u >> 6, l = u & 63;
    int n = n0 + rr;
    float x0 = data[(n * T_ + t) * 2 + 0];
    float x1 = data[(n * T_ + t) * 2 + 1];
    Xcur[(size_t)n * KX + l] =
        f2bf(fmaxf(x0 * W_r[l * 2] + x1 * W_r[l * 2 + 1] + b_r[l], 0.f));
  }
  if (t == 0) {
    for (int i = tid; i < 64 * 64; i += 512) shw2[i] = 0.f;
    u16x8 z = (u16x8){0, 0, 0, 0, 0, 0, 0, 0};
    int row = tid >> 5, c8 = tid & 31;
    *(u16x8*)(Xcur + (size_t)(n0 + row) * KX + 576 + c8 * 8) = z;
  } else {
    int w = tid >> 6, lane = tid & 63;
    int lr = lane & 15, lh = lane >> 4;
    const unsigned short* a0p = Xcur + (size_t)(b * A_ + w * 16 + lr) * KX + 576 + lh * 8;
    const unsigned short* b0p = Web + lr * HS + lh * 8;
    const unsigned short* b1p = Web + (16 + lr) * HS + lh * 8;
    f4_t hacc[2];
    hacc[0] = (f4_t){0.f, 0.f, 0.f, 0.f}; hacc[1] = hacc[0];
    #pragma unroll
    for (int kk = 0; kk < 8; ++kk) {
      bf8_t av  = *(const bf8_t*)(a0p + kk * 32);
      bf8_t bv0 = *(const bf8_t*)(b0p + kk * 32);
      bf8_t bv1 = *(const bf8_t*)(b1p + kk * 32);
      hacc[0] = __builtin_amdgcn_mfma_f32_16x16x32_bf16(av, bv0, hacc[0], 0, 0, 0);
      hacc[1] = __builtin_amdgcn_mfma_f32_16x16x32_bf16(av, bv1, hacc[1], 0, 0, 0);
    }
    int ccol = lane & 15, crow4 = (lane >> 4) * 4;
    #pragma unroll
    for (int cb2 = 0; cb2 < 2; ++cb2)
      #pragma unroll
      for (int j = 0; j < 4; ++j) {
        int rr = w * 16 + crow4 + j;
        int c  = cb2 * 16 + ccol;
        shw2[(rr >> 1) * 64 + c * 2 + (rr & 1)] = hacc[cb2][j];
      }
  }
  __syncthreads();

  for (int u = tid; u < 1024; u += 512) {
    int r = u >> 6, jp = u & 63;
    int irow = ig8 * 16 + r;
    float xi = sx[irow], yi = sy[irow];
    bool acti = xi >= 0.f;
    float m0[4], m1[4], nn0[4], nn1[4];
    #pragma unroll
    for (int s = 0; s < 2; ++s) {
      int j = jp * 2 + s;
      float xj = sx[j], yj = sy[j];
      bool v = acti && (xj >= 0.f) && (j != irow);
      float dx = xi - xj, dy = yi - yj;
      float* mm = s ? m1 : m0;
      float* nn = s ? nn1 : nn0;
      mm[0] = (v && dx >= 8.f   && dx <= 16.f) ? 1.f : 0.f;
      mm[1] = (v && dx >= 0.f   && dx <= 8.f ) ? 1.f : 0.f;
      mm[2] = (v && dx >= -8.f  && dx <= 0.f ) ? 1.f : 0.f;
      mm[3] = (v && dx >= -16.f && dx <= -8.f) ? 1.f : 0.f;
      nn[0] = (dy >= -16.f && dy <= -8.f) ? 1.f : 0.f;
      nn[1] = (dy >= -8.f  && dy <= 0.f ) ? 1.f : 0.f;
      nn[2] = (dy >= 0.f   && dy <= 8.f ) ? 1.f : 0.f;
      nn[3] = (dy >= 8.f   && dy <= 16.f) ? 1.f : 0.f;
    }
    float4* px = (float4*)&smx[r][jp][0];
    px[0] = (float4){m0[0], m1[0], m0[1], m1[1]};
    px[1] = (float4){m0[2], m1[2], m0[3], m1[3]};
    float4* py = (float4*)&smy[r][jp][0];
    py[0] = (float4){nn0[0], nn1[0], nn0[1], nn1[1]};
    py[1] = (float4){nn0[2], nn1[2], nn0[3], nn1[3]};
  }
  __syncthreads();

  int half = tid >> 5;               // row 0..15
  int lane = tid & 31;               // channel
  f2_t acc[16];
  #pragma unroll
  for (int g = 0; g < 16; ++g) acc[g] = (f2_t){0.f, 0.f};
  #pragma unroll 2
  for (int jp = 0; jp < 64; ++jp) {
    f2_t hv = *(const f2_t*)&shw2[jp * 64 + lane * 2];
    float4 xa = ((const float4*)&smx[half][jp][0])[0];
    float4 xb = ((const float4*)&smx[half][jp][0])[1];
    float4 ya = ((const float4*)&smy[half][jp][0])[0];
    float4 yb = ((const float4*)&smy[half][jp][0])[1];
    f2_t mx[4] = {(f2_t){xa.x, xa.y}, (f2_t){xa.z, xa.w},
                  (f2_t){xb.x, xb.y}, (f2_t){xb.z, xb.w}};
    f2_t p[4]  = {(f2_t){ya.x, ya.y} * hv, (f2_t){ya.z, ya.w} * hv,
                  (f2_t){yb.x, yb.y} * hv, (f2_t){yb.z, yb.w} * hv};
    #pragma unroll
    for (int gy = 0; gy < 4; ++gy)
      #pragma unroll
      for (int gx = 0; gx < 4; ++gx)
        acc[gy * 4 + gx] += mx[gx] * p[gy];
  }

  int irow = ig8 * 16 + half;
  float be = b_e[lane];
  int hi = irow >> 4;                // == ig8
  int klo = (irow & 15) * ES + lane;
  #pragma unroll
  for (int g = 0; g < 16; ++g) {
    float e = fmaxf(acc[g][0] + acc[g][1] + be, 0.f);
    int a_out = g * 8 + hi;
    Xcur[(size_t)(b * A_ + a_out) * KX + 64 + klo] = f2bf(e);
  }
}

// ---- gates GEMM + register-direct LSTM pointwise (R10 measured-best shape).
// BM=128, BN=128, BK=32, 512 thr, grid 256 (tm=bid&31 -> XCD=b%8).
// 4-buffer rotation, counted vmcnt(2), raw s_barrier.
__global__ __launch_bounds__(512) void k_gemm_lstm(
    const unsigned short* __restrict__ Xcur, const unsigned short* __restrict__ Wc,
    const float* __restrict__ bsum,
    float* __restrict__ cbuf, unsigned short* __restrict__ Xnext, int t) {
  __shared__ unsigned short sA0[128 * 32], sB0[128 * 32];   // 8 KB each
  __shared__ unsigned short sA1[128 * 32], sB1[128 * 32];
  __shared__ unsigned short sA2[128 * 32], sB2[128 * 32];
  __shared__ unsigned short sA3[128 * 32], sB3[128 * 32];   // total 64 KB

  int bid = blockIdx.x;
  int tm = bid & 31, tc = bid >> 5;
  int row0 = tm * 128, col0 = tc * 128;
  int tid = threadIdx.x;
  int lane = tid & 63;
  int w = tid >> 6;
  int wr = w >> 1, wc = w & 1;              // 8 waves: 32 rows x 64 cols each
  int lr = lane & 15, lh = lane >> 4;

  // staging: thread -> (row tid>>2, chunk tid&3); global chunk pre-swizzled
  int srow = tid >> 2, schunk = tid & 3;
  int gch = (schunk ^ ((srow >> 1) & 3)) * 8;
  const unsigned short* gA = Xcur + (size_t)(row0 + srow) * KX + gch;
  const unsigned short* gB = Wc  + (size_t)(col0 + srow) * KX + gch;

  int swz = (lh ^ ((lr >> 1) & 3)) * 8;
  int aoff[2], boff[4];
  #pragma unroll
  for (int m = 0; m < 2; ++m) aoff[m] = (wr * 32 + m * 16 + lr) * 32 + swz;
  #pragma unroll
  for (int n = 0; n < 4; ++n) boff[n] = (wc * 64 + n * 16 + lr) * 32 + swz;

  f4_t acc[2][4];
  #pragma unroll
  for (int m = 0; m < 2; ++m)
    #pragma unroll
    for (int n = 0; n < 4; ++n) acc[m][n] = (f4_t){0.f, 0.f, 0.f, 0.f};

#define STAGE(pA, pB, kt) do { \
    gload16(gA + (size_t)(kt) * 32, (pA) + tid * 8); \
    gload16(gB + (size_t)(kt) * 32, (pB) + tid * 8); \
  } while (0)

#define COMPUTE(pA, pB) do { \
    bf8_t a_[2], b_[4]; \
    _Pragma("unroll") for (int m = 0; m < 2; ++m) a_[m] = *(const bf8_t*)((pA) + aoff[m]); \
    _Pragma("unroll") for (int n = 0; n < 4; ++n) b_[n] = *(const bf8_t*)((pB) + boff[n]); \
    _Pragma("unroll") for (int m = 0; m < 2; ++m) \
      _Pragma("unroll") for (int n = 0; n < 4; ++n) \
        acc[m][n] = __builtin_amdgcn_mfma_f32_16x16x32_bf16(a_[m], b_[n], acc[m][n], 0, 0, 0); \
  } while (0)

// stage kt ready (vmcnt(2): kt+1's 2 loads stay in flight), prefetch kt+2,
// compute kt.
#define ITER(AC, BC, AN, BN, kt) do { \
    asm volatile("s_waitcnt vmcnt(2)" ::: "memory"); \
    __builtin_amdgcn_sched_barrier(0); \
    __builtin_amdgcn_s_barrier(); \
    STAGE(AN, BN, (kt) + 2); \
    COMPUTE(AC, BC); \
  } while (0)

  STAGE(sA0, sB0, 0);
  STAGE(sA1, sB1, 1);
  #pragma unroll 1
  for (int kt = 0; kt < 24; kt += 4) {
    ITER(sA0, sB0, sA2, sB2, kt);
    ITER(sA1, sB1, sA3, sB3, kt + 1);
    ITER(sA2, sB2, sA0, sB0, kt + 2);
    ITER(sA3, sB3, sA1, sB1, kt + 3);
  }
  // kt = 24: ready when only stage-25's 2 loads remain
  asm volatile("s_waitcnt vmcnt(2)" ::: "memory");
  __builtin_amdgcn_sched_barrier(0);
  __builtin_amdgcn_s_barrier();
  COMPUTE(sA0, sB0);
  // kt = 25: drain fully
  asm volatile("s_waitcnt vmcnt(0)" ::: "memory");
  __builtin_amdgcn_sched_barrier(0);
  __builtin_amdgcn_s_barrier();
  COMPUTE(sA1, sB1);
#undef ITER
#undef STAGE
#undef COMPUTE

  // register-direct LSTM pointwise: lane owns channel ch = (tc*2+wc)*16+q
  int q = lane & 15;
  float bias_g[4];
  #pragma unroll
  for (int n = 0; n < 4; ++n) bias_g[n] = bsum[col0 + wc * 64 + n * 16 + q];
  int ch = (tc * 2 + wc) * 16 + q;
  int jrow4 = (lane >> 4) * 4;
  #pragma unroll
  for (int m = 0; m < 2; ++m) {
    #pragma unroll
    for (int j = 0; j < 4; ++j) {
      int row = row0 + wr * 32 + m * 16 + jrow4 + j;
      float ig = acc[m][0][j] + bias_g[0];
      float fg = acc[m][1][j] + bias_g[1];
      float gg = acc[m][2][j] + bias_g[2];
      float og = acc[m][3][j] + bias_g[3];
      float cold = (t == 0) ? 0.f : cbuf[(size_t)row * HS + ch];
      float c2 = sigm(fg) * cold + sigm(ig) * tanhf(gg);
      float h2 = sigm(og) * tanhf(c2);
      cbuf[(size_t)row * HS + ch] = c2;
      Xnext[(size_t)row * KX + 576 + ch] = f2bf(h2);
    }
  }
}

// ---- final head for t=63 (512 blocks x 8 rows); Xh = X holding h2(63)
__global__ __launch_bounds__(256) void k_fin(
    const float* __restrict__ data, const float* __restrict__ W_r,
    const float* __restrict__ b_r, const float* __restrict__ Whead,
    const float* __restrict__ bhead, const unsigned short* __restrict__ Xh,
    float* __restrict__ out) {
  head_fin_dev(data, W_r, b_r, Whead, bhead, Xh, out,
               blockIdx.x * 8, T_ - 1, threadIdx.x);
}

extern "C" void kernel_launch(void* const* d_in, const int* in_sizes, int n_in,
                              void* d_out, int out_size, void* d_ws, size_t ws_size,
                              hipStream_t stream) {
  const float* data = (const float*)d_in[0];
  const float* W_r  = (const float*)d_in[2];
  const float* b_r  = (const float*)d_in[3];
  const float* W_e  = (const float*)d_in[4];
  const float* b_e  = (const float*)d_in[5];
  const float* W_ih = (const float*)d_in[6];
  const float* W_hh = (const float*)d_in[7];
  const float* b_ih = (const float*)d_in[8];
  const float* b_hh = (const float*)d_in[9];
  const float* W_p  = (const float*)d_in[10];
  const float* b_p  = (const float*)d_in[11];
  const float* W_p2 = (const float*)d_in[12];
  const float* b_p2 = (const float*)d_in[13];
  const float* W_mu = (const float*)d_in[14];
  const float* b_mu = (const float*)d_in[15];
  const float* W_sd = (const float*)d_in[16];
  const float* b_sd = (const float*)d_in[17];
  const float* W_cr = (const float*)d_in[18];
  const float* b_cr = (const float*)d_in[19];
  float* out = (float*)d_out;

  char* ws = (char*)d_ws;
  float* cbuf  = (float*)(ws);                                // 4 MB
  unsigned short* Xbf0 = (unsigned short*)(ws + (4u  << 20)); // 6.5 MB
  unsigned short* Xbf1 = (unsigned short*)(ws + (11u << 20)); // 6.5 MB
  unsigned short* Wc   = (unsigned short*)(ws + (18u << 20)); // 1.7 MB
  float* bsum  = (float*)(ws + (20u << 20));                  // 4 KB
  float* Whead = (float*)(ws + (20u << 20) + 8192);           // 6.4 KB
  float* bhead = (float*)(ws + (20u << 20) + 16384);          // 20 B
  unsigned short* Web = (unsigned short*)(ws + (20u << 20) + 20480); // 16 KB

  k_wcat<<<(GD * KX + GD + ES * HS + 255) / 256, 256, 0, stream>>>(
      W_ih, W_hh, b_ih, b_hh, W_e, Wc, bsum, Web);
  k_head<<<5, 320, 0, stream>>>(W_p, b_p, W_p2, b_p2, W_mu, b_mu, W_sd, b_sd, W_cr, b_cr,
                                Whead, bhead);

  for (int t = 0; t < T_; ++t) {
    unsigned short* Xcur  = (t & 1) ? Xbf1 : Xbf0;
    unsigned short* Xnext = (t & 1) ? Xbf0 : Xbf1;
    k_social<<<256, 512, 0, stream>>>(data, Web, b_e, Xcur, Whead, bhead,
                                      W_r, b_r, out, t);
    k_gemm_lstm<<<256, 512, 0, stream>>>(Xcur, Wc, bsum, cbuf, Xnext, t);
  }
  // h2(63) lives in Xnext of t=63 -> Xbf0 (t=63 odd)
  k_fin<<<512, 256, 0, stream>>>(data, W_r, b_r, Whead, bhead, Xbf0, out);
}

// Round 14
// 1989.065 us; speedup vs baseline: 1.0759x; 1.0009x over previous
//
#include <hip/hip_runtime.h>
#include <hip/hip_bf16.h>

#define B_  32
#define A_  128
#define T_  64
#define N_  4096        // B_*A_
#define HS  256
#define ES  32
#define RS  64
#define KX  832         // 64 (r) + 512 (e) + 256 (h)
#define GD  1024        // 4*HS
#define NKT 26          // KX/32

typedef __attribute__((ext_vector_type(8))) short bf8_t;            // 8 x bf16
typedef __attribute__((ext_vector_type(8))) unsigned short u16x8;
typedef __attribute__((ext_vector_type(4))) float f4_t;             // mfma acc
typedef __attribute__((ext_vector_type(2))) float f2_t;

__device__ __forceinline__ unsigned short f2bf(float x) {
  union { float f; unsigned u; } v; v.f = x;
  unsigned u = v.u;
  u += 0x7fffu + ((u >> 16) & 1u);     // round-to-nearest-even
  return (unsigned short)(u >> 16);
}
__device__ __forceinline__ float bf2f(unsigned short u) {
  union { unsigned u; float f; } v; v.u = ((unsigned)u) << 16; return v.f;
}
__device__ __forceinline__ float sigm(float x) { return 1.f / (1.f + __expf(-x)); }

__device__ __forceinline__ void gload16(const void* g, void* l) {
  __builtin_amdgcn_global_load_lds((const __attribute__((address_space(1))) void*)g,
                                   (__attribute__((address_space(3))) void*)l, 16, 0, 0);
}

// ---- Wc (permuted) + fused bias + bf16 W_e copy
__global__ void k_wcat(const float* __restrict__ W_ih, const float* __restrict__ W_hh,
                       const float* __restrict__ b_ih, const float* __restrict__ b_hh,
                       const float* __restrict__ W_e,
                       unsigned short* __restrict__ Wc, float* __restrict__ bsum,
                       unsigned short* __restrict__ Web) {
  int i = blockIdx.x * 256 + threadIdx.x;
  if (i < GD * KX) {
    int mp = i / KX, k = i - mp * KX;
    int nb = mp >> 6, rem = mp & 63, g = rem >> 4, q = rem & 15;
    int mo = g * 256 + nb * 16 + q;
    float v = (k < 576) ? W_ih[mo * 576 + k] : W_hh[mo * 256 + (k - 576)];
    Wc[i] = f2bf(v);
  } else if (i < GD * KX + GD) {
    int j = i - GD * KX;
    int nb = j >> 6, rem = j & 63, g = rem >> 4, q = rem & 15;
    int mo = g * 256 + nb * 16 + q;
    bsum[j] = b_ih[mo] + b_hh[mo];
  } else if (i < GD * KX + GD + ES * HS) {
    int j2 = i - GD * KX - GD;
    Web[j2] = f2bf(W_e[j2]);
  }
}

// ---- collapsed head: Whead[o][320] = (Wo @ W_p2) @ W_p   (5 blocks x 320 thr)
__global__ __launch_bounds__(320) void k_head(
    const float* __restrict__ W_p, const float* __restrict__ b_p,
    const float* __restrict__ W_p2, const float* __restrict__ b_p2,
    const float* __restrict__ W_mu, const float* __restrict__ b_mu,
    const float* __restrict__ W_sd, const float* __restrict__ b_sd,
    const float* __restrict__ W_cr, const float* __restrict__ b_cr,
    float* __restrict__ Whead, float* __restrict__ bhead) {
  int o = blockIdx.x, tid = threadIdx.x;
  __shared__ float to[64];
  const float* Wo = (o < 2) ? W_mu + o * 32 : (o < 4) ? W_sd + (o - 2) * 32 : W_cr;
  if (tid < 64) {
    float a = 0.f;
    #pragma unroll 8
    for (int c = 0; c < 32; ++c) a += Wo[c] * W_p2[c * 64 + tid];
    to[tid] = a;
  }
  __syncthreads();
  float a = 0.f;
  #pragma unroll 8
  for (int j = 0; j < 64; ++j) a += to[j] * W_p[j * 320 + tid];
  Whead[o * 320 + tid] = a;
  if (tid == 0) {
    float b0 = (o < 2) ? b_mu[o] : (o < 4) ? b_sd[o - 2] : b_cr[0];
    float acc = b0;
    for (int c = 0; c < 32; ++c) acc += Wo[c] * b_p2[c];
    for (int j = 0; j < 64; ++j) acc += to[j] * b_p[j];
    bhead[o] = acc;
  }
}

// ---- head for step ts, rows n0..n0+(threads/32). h2(ts) = bf16 h-part of Xh.
__device__ __forceinline__ void head_fin_dev(
    const float* __restrict__ data, const float* __restrict__ W_r,
    const float* __restrict__ b_r, const float* __restrict__ Whead,
    const float* __restrict__ bhead, const unsigned short* __restrict__ Xh,
    float* __restrict__ out, int n0, int ts, int tid) {
  int r8 = tid >> 5, ln = tid & 31;
  int n = n0 + r8;
  float s0 = 0.f, s1 = 0.f, s2 = 0.f, s3 = 0.f, s4 = 0.f;
  u16x8 hv = *(const u16x8*)(Xh + (size_t)n * KX + 576 + ln * 8);
  float hf[8];
  #pragma unroll
  for (int k = 0; k < 8; ++k) hf[k] = bf2f(hv[k]);
  #pragma unroll
  for (int k = 0; k < 8; ++k) {
    int kk = 64 + ln * 8 + k;
    s0 += hf[k] * Whead[0 * 320 + kk];
    s1 += hf[k] * Whead[1 * 320 + kk];
    s2 += hf[k] * Whead[2 * 320 + kk];
    s3 += hf[k] * Whead[3 * 320 + kk];
    s4 += hf[k] * Whead[4 * 320 + kk];
  }
  float x0 = data[(n * T_ + ts) * 2 + 0];
  float x1 = data[(n * T_ + ts) * 2 + 1];
  #pragma unroll
  for (int l2 = 0; l2 < 2; ++l2) {
    int l = ln + 32 * l2;
    float rv = fmaxf(x0 * W_r[l * 2] + x1 * W_r[l * 2 + 1] + b_r[l], 0.f);
    s0 += rv * Whead[0 * 320 + l];
    s1 += rv * Whead[1 * 320 + l];
    s2 += rv * Whead[2 * 320 + l];
    s3 += rv * Whead[3 * 320 + l];
    s4 += rv * Whead[4 * 320 + l];
  }
  #pragma unroll
  for (int off = 16; off; off >>= 1) {
    s0 += __shfl_xor(s0, off);
    s1 += __shfl_xor(s1, off);
    s2 += __shfl_xor(s2, off);
    s3 += __shfl_xor(s3, off);
    s4 += __shfl_xor(s4, off);
  }
  if (ln == 0) {
    out[(n * T_ + ts) * 2 + 0] = s0 + bhead[0];
    out[(n * T_ + ts) * 2 + 1] = s1 + bhead[1];
    out[N_ * T_ * 2 + (n * T_ + ts) * 2 + 0] = __expf(s2 + bhead[2]);
    out[N_ * T_ * 2 + (n * T_ + ts) * 2 + 1] = __expf(s3 + bhead[3]);
    out[N_ * T_ * 4 + n * T_ + ts] = tanhf(s4 + bhead[4]);
  }
}

// ---- social (256 blocks x 512 thr; block = (b, ig8) owning 16 rows)
// XCD-aligned: b = bid&31 -> XCD(bid)=b%8, matches gemm's tm mapping.
__global__ __launch_bounds__(512) void k_social(
    const float* __restrict__ data, const unsigned short* __restrict__ Web,
    const float* __restrict__ b_e, unsigned short* __restrict__ Xcur,
    const float* __restrict__ Whead, const float* __restrict__ bhead,
    const float* __restrict__ W_r, const float* __restrict__ b_r,
    float* __restrict__ out, int t) {
  int b   = blockIdx.x & 31;
  int ig8 = blockIdx.x >> 5;
  int n0  = b * A_ + ig8 * 16;
  __shared__ float sx[A_], sy[A_];
  __shared__ float shw2[64 * 64];       // [jp][c][sub]  16 KB
  __shared__ float smx[16][64][8];      // 32 KB
  __shared__ float smy[16][64][8];      // 32 KB
  int tid = threadIdx.x;
  if (tid < A_) {
    sx[tid] = data[((b * A_ + tid) * T_ + t) * 2 + 0];
    sy[tid] = data[((b * A_ + tid) * T_ + t) * 2 + 1];
  }
  if (t > 0)
    head_fin_dev(data, W_r, b_r, Whead, bhead, Xcur, out, n0, t - 1, tid);
  for (int u = tid; u < 1024; u += 512) {
    int rr = u >> 6, l = u & 63;
    int n = n0 + rr;
    float x0 = data[(n * T_ + t) * 2 + 0];
    float x1 = data[(n * T_ + t) * 2 + 1];
    Xcur[(size_t)n * KX + l] =
        f2bf(fmaxf(x0 * W_r[l * 2] + x1 * W_r[l * 2 + 1] + b_r[l], 0.f));
  }
  if (t == 0) {
    for (int i = tid; i < 64 * 64; i += 512) shw2[i] = 0.f;
    u16x8 z = (u16x8){0, 0, 0, 0, 0, 0, 0, 0};
    int row = tid >> 5, c8 = tid & 31;
    *(u16x8*)(Xcur + (size_t)(n0 + row) * KX + 576 + c8 * 8) = z;
  } else {
    int w = tid >> 6, lane = tid & 63;
    int lr = lane & 15, lh = lane >> 4;
    const unsigned short* a0p = Xcur + (size_t)(b * A_ + w * 16 + lr) * KX + 576 + lh * 8;
    const unsigned short* b0p = Web + lr * HS + lh * 8;
    const unsigned short* b1p = Web + (16 + lr) * HS + lh * 8;
    f4_t hacc[2];
    hacc[0] = (f4_t){0.f, 0.f, 0.f, 0.f}; hacc[1] = hacc[0];
    #pragma unroll
    for (int kk = 0; kk < 8; ++kk) {
      bf8_t av  = *(const bf8_t*)(a0p + kk * 32);
      bf8_t bv0 = *(const bf8_t*)(b0p + kk * 32);
      bf8_t bv1 = *(const bf8_t*)(b1p + kk * 32);
      hacc[0] = __builtin_amdgcn_mfma_f32_16x16x32_bf16(av, bv0, hacc[0], 0, 0, 0);
      hacc[1] = __builtin_amdgcn_mfma_f32_16x16x32_bf16(av, bv1, hacc[1], 0, 0, 0);
    }
    int ccol = lane & 15, crow4 = (lane >> 4) * 4;
    #pragma unroll
    for (int cb2 = 0; cb2 < 2; ++cb2)
      #pragma unroll
      for (int j = 0; j < 4; ++j) {
        int rr = w * 16 + crow4 + j;
        int c  = cb2 * 16 + ccol;
        shw2[(rr >> 1) * 64 + c * 2 + (rr & 1)] = hacc[cb2][j];
      }
  }
  __syncthreads();

  for (int u = tid; u < 1024; u += 512) {
    int r = u >> 6, jp = u & 63;
    int irow = ig8 * 16 + r;
    float xi = sx[irow], yi = sy[irow];
    bool acti = xi >= 0.f;
    float m0[4], m1[4], nn0[4], nn1[4];
    #pragma unroll
    for (int s = 0; s < 2; ++s) {
      int j = jp * 2 + s;
      float xj = sx[j], yj = sy[j];
      bool v = acti && (xj >= 0.f) && (j != irow);
      float dx = xi - xj, dy = yi - yj;
      float* mm = s ? m1 : m0;
      float* nn = s ? nn1 : nn0;
      mm[0] = (v && dx >= 8.f   && dx <= 16.f) ? 1.f : 0.f;
      mm[1] = (v && dx >= 0.f   && dx <= 8.f ) ? 1.f : 0.f;
      mm[2] = (v && dx >= -8.f  && dx <= 0.f ) ? 1.f : 0.f;
      mm[3] = (v && dx >= -16.f && dx <= -8.f) ? 1.f : 0.f;
      nn[0] = (dy >= -16.f && dy <= -8.f) ? 1.f : 0.f;
      nn[1] = (dy >= -8.f  && dy <= 0.f ) ? 1.f : 0.f;
      nn[2] = (dy >= 0.f   && dy <= 8.f ) ? 1.f : 0.f;
      nn[3] = (dy >= 8.f   && dy <= 16.f) ? 1.f : 0.f;
    }
    float4* px = (float4*)&smx[r][jp][0];
    px[0] = (float4){m0[0], m1[0], m0[1], m1[1]};
    px[1] = (float4){m0[2], m1[2], m0[3], m1[3]};
    float4* py = (float4*)&smy[r][jp][0];
    py[0] = (float4){nn0[0], nn1[0], nn0[1], nn1[1]};
    py[1] = (float4){nn0[2], nn1[2], nn0[3], nn1[3]};
  }
  __syncthreads();

  int half = tid >> 5;               // row 0..15
  int lane = tid & 31;               // channel
  f2_t acc[16];
  #pragma unroll
  for (int g = 0; g < 16; ++g) acc[g] = (f2_t){0.f, 0.f};
  #pragma unroll 2
  for (int jp = 0; jp < 64; ++jp) {
    f2_t hv = *(const f2_t*)&shw2[jp * 64 + lane * 2];
    float4 xa = ((const float4*)&smx[half][jp][0])[0];
    float4 xb = ((const float4*)&smx[half][jp][0])[1];
    float4 ya = ((const float4*)&smy[half][jp][0])[0];
    float4 yb = ((const float4*)&smy[half][jp][0])[1];
    f2_t mx[4] = {(f2_t){xa.x, xa.y}, (f2_t){xa.z, xa.w},
                  (f2_t){xb.x, xb.y}, (f2_t){xb.z, xb.w}};
    f2_t p[4]  = {(f2_t){ya.x, ya.y} * hv, (f2_t){ya.z, ya.w} * hv,
                  (f2_t){yb.x, yb.y} * hv, (f2_t){yb.z, yb.w} * hv};
    #pragma unroll
    for (int gy = 0; gy < 4; ++gy)
      #pragma unroll
      for (int gx = 0; gx < 4; ++gx)
        acc[gy * 4 + gx] += mx[gx] * p[gy];
  }

  int irow = ig8 * 16 + half;
  float be = b_e[lane];
  int hi = irow >> 4;                // == ig8
  int klo = (irow & 15) * ES + lane;
  #pragma unroll
  for (int g = 0; g < 16; ++g) {
    float e = fmaxf(acc[g][0] + acc[g][1] + be, 0.f);
    int a_out = g * 8 + hi;
    Xcur[(size_t)(b * A_ + a_out) * KX + 64 + klo] = f2bf(e);
  }
}

// ---- gates GEMM + register-direct LSTM pointwise.
// BM=128, BN=128, BK=32, 512 thr, grid 256 (tm=bid&31 -> XCD=b%8).
// 5-buffer rotation, lookahead-3, counted vmcnt(4), raw s_barrier.
// cbuf is f16 (_Float16) to halve c-state traffic.
__global__ __launch_bounds__(512) void k_gemm_lstm(
    const unsigned short* __restrict__ Xcur, const unsigned short* __restrict__ Wc,
    const float* __restrict__ bsum,
    _Float16* __restrict__ cbuf, unsigned short* __restrict__ Xnext, int t) {
  __shared__ unsigned short sA0[128 * 32], sB0[128 * 32];   // 8 KB each
  __shared__ unsigned short sA1[128 * 32], sB1[128 * 32];
  __shared__ unsigned short sA2[128 * 32], sB2[128 * 32];
  __shared__ unsigned short sA3[128 * 32], sB3[128 * 32];
  __shared__ unsigned short sA4[128 * 32], sB4[128 * 32];   // total 80 KB

  int bid = blockIdx.x;
  int tm = bid & 31, tc = bid >> 5;
  int row0 = tm * 128, col0 = tc * 128;
  int tid = threadIdx.x;
  int lane = tid & 63;
  int w = tid >> 6;
  int wr = w >> 1, wc = w & 1;              // 8 waves: 32 rows x 64 cols each
  int lr = lane & 15, lh = lane >> 4;

  // staging: thread -> (row tid>>2, chunk tid&3); global chunk pre-swizzled
  int srow = tid >> 2, schunk = tid & 3;
  int gch = (schunk ^ ((srow >> 1) & 3)) * 8;
  const unsigned short* gA = Xcur + (size_t)(row0 + srow) * KX + gch;
  const unsigned short* gB = Wc  + (size_t)(col0 + srow) * KX + gch;

  int swz = (lh ^ ((lr >> 1) & 3)) * 8;
  int aoff[2], boff[4];
  #pragma unroll
  for (int m = 0; m < 2; ++m) aoff[m] = (wr * 32 + m * 16 + lr) * 32 + swz;
  #pragma unroll
  for (int n = 0; n < 4; ++n) boff[n] = (wc * 64 + n * 16 + lr) * 32 + swz;

  f4_t acc[2][4];
  #pragma unroll
  for (int m = 0; m < 2; ++m)
    #pragma unroll
    for (int n = 0; n < 4; ++n) acc[m][n] = (f4_t){0.f, 0.f, 0.f, 0.f};

#define STAGE(pA, pB, kt) do { \
    gload16(gA + (size_t)(kt) * 32, (pA) + tid * 8); \
    gload16(gB + (size_t)(kt) * 32, (pB) + tid * 8); \
  } while (0)

#define COMPUTE(pA, pB) do { \
    bf8_t a_[2], b_[4]; \
    _Pragma("unroll") for (int m = 0; m < 2; ++m) a_[m] = *(const bf8_t*)((pA) + aoff[m]); \
    _Pragma("unroll") for (int n = 0; n < 4; ++n) b_[n] = *(const bf8_t*)((pB) + boff[n]); \
    _Pragma("unroll") for (int m = 0; m < 2; ++m) \
      _Pragma("unroll") for (int n = 0; n < 4; ++n) \
        acc[m][n] = __builtin_amdgcn_mfma_f32_16x16x32_bf16(a_[m], b_[n], acc[m][n], 0, 0, 0); \
  } while (0)

// stage kt ready (vmcnt(4): kt+1,kt+2's 4 loads stay in flight),
// prefetch kt+3 into buffer (kt+3)%5 (= buffer of kt-2, read-complete), compute kt.
#define ITER(AC, BC, AN, BN, kt) do { \
    asm volatile("s_waitcnt vmcnt(4)" ::: "memory"); \
    __builtin_amdgcn_sched_barrier(0); \
    __builtin_amdgcn_s_barrier(); \
    STAGE(AN, BN, (kt) + 3); \
    COMPUTE(AC, BC); \
  } while (0)

  STAGE(sA0, sB0, 0);
  STAGE(sA1, sB1, 1);
  STAGE(sA2, sB2, 2);
  #pragma unroll 1
  for (int kt = 0; kt < 20; kt += 5) {
    ITER(sA0, sB0, sA3, sB3, kt);
    ITER(sA1, sB1, sA4, sB4, kt + 1);
    ITER(sA2, sB2, sA0, sB0, kt + 2);
    ITER(sA3, sB3, sA1, sB1, kt + 3);
    ITER(sA4, sB4, sA2, sB2, kt + 4);
  }
  ITER(sA0, sB0, sA3, sB3, 20);   // prefetch 23
  ITER(sA1, sB1, sA4, sB4, 21);   // prefetch 24
  ITER(sA2, sB2, sA0, sB0, 22);   // prefetch 25
  // kt = 23 (buf 3): outstanding = stages 24,25 (4 loads)
  asm volatile("s_waitcnt vmcnt(4)" ::: "memory");
  __builtin_amdgcn_sched_barrier(0);
  __builtin_amdgcn_s_barrier();
  COMPUTE(sA3, sB3);
  // kt = 24 (buf 4)
  asm volatile("s_waitcnt vmcnt(2)" ::: "memory");
  __builtin_amdgcn_sched_barrier(0);
  __builtin_amdgcn_s_barrier();
  COMPUTE(sA4, sB4);
  // kt = 25 (buf 0)
  asm volatile("s_waitcnt vmcnt(0)" ::: "memory");
  __builtin_amdgcn_sched_barrier(0);
  __builtin_amdgcn_s_barrier();
  COMPUTE(sA0, sB0);
#undef ITER
#undef STAGE
#undef COMPUTE

  // register-direct LSTM pointwise: lane owns channel ch = (tc*2+wc)*16+q
  int q = lane & 15;
  float bias_g[4];
  #pragma unroll
  for (int n = 0; n < 4; ++n) bias_g[n] = bsum[col0 + wc * 64 + n * 16 + q];
  int ch = (tc * 2 + wc) * 16 + q;
  int jrow4 = (lane >> 4) * 4;
  #pragma unroll
  for (int m = 0; m < 2; ++m) {
    #pragma unroll
    for (int j = 0; j < 4; ++j) {
      int row = row0 + wr * 32 + m * 16 + jrow4 + j;
      float ig = acc[m][0][j] + bias_g[0];
      float fg = acc[m][1][j] + bias_g[1];
      float gg = acc[m][2][j] + bias_g[2];
      float og = acc[m][3][j] + bias_g[3];
      float cold = (t == 0) ? 0.f : (float)cbuf[(size_t)row * HS + ch];
      float c2 = sigm(fg) * cold + sigm(ig) * tanhf(gg);
      float h2 = sigm(og) * tanhf(c2);
      cbuf[(size_t)row * HS + ch] = (_Float16)c2;
      Xnext[(size_t)row * KX + 576 + ch] = f2bf(h2);
    }
  }
}

// ---- final head for t=63 (512 blocks x 8 rows); Xh = X holding h2(63)
__global__ __launch_bounds__(256) void k_fin(
    const float* __restrict__ data, const float* __restrict__ W_r,
    const float* __restrict__ b_r, const float* __restrict__ Whead,
    const float* __restrict__ bhead, const unsigned short* __restrict__ Xh,
    float* __restrict__ out) {
  head_fin_dev(data, W_r, b_r, Whead, bhead, Xh, out,
               blockIdx.x * 8, T_ - 1, threadIdx.x);
}

extern "C" void kernel_launch(void* const* d_in, const int* in_sizes, int n_in,
                              void* d_out, int out_size, void* d_ws, size_t ws_size,
                              hipStream_t stream) {
  const float* data = (const float*)d_in[0];
  const float* W_r  = (const float*)d_in[2];
  const float* b_r  = (const float*)d_in[3];
  const float* W_e  = (const float*)d_in[4];
  const float* b_e  = (const float*)d_in[5];
  const float* W_ih = (const float*)d_in[6];
  const float* W_hh = (const float*)d_in[7];
  const float* b_ih = (const float*)d_in[8];
  const float* b_hh = (const float*)d_in[9];
  const float* W_p  = (const float*)d_in[10];
  const float* b_p  = (const float*)d_in[11];
  const float* W_p2 = (const float*)d_in[12];
  const float* b_p2 = (const float*)d_in[13];
  const float* W_mu = (const float*)d_in[14];
  const float* b_mu = (const float*)d_in[15];
  const float* W_sd = (const float*)d_in[16];
  const float* b_sd = (const float*)d_in[17];
  const float* W_cr = (const float*)d_in[18];
  const float* b_cr = (const float*)d_in[19];
  float* out = (float*)d_out;

  char* ws = (char*)d_ws;
  _Float16* cbuf = (_Float16*)(ws);                           // 2 MB
  unsigned short* Xbf0 = (unsigned short*)(ws + (4u  << 20)); // 6.5 MB
  unsigned short* Xbf1 = (unsigned short*)(ws + (11u << 20)); // 6.5 MB
  unsigned short* Wc   = (unsigned short*)(ws + (18u << 20)); // 1.7 MB
  float* bsum  = (float*)(ws + (20u << 20));                  // 4 KB
  float* Whead = (float*)(ws + (20u << 20) + 8192);           // 6.4 KB
  float* bhead = (float*)(ws + (20u << 20) + 16384);          // 20 B
  unsigned short* Web = (unsigned short*)(ws + (20u << 20) + 20480); // 16 KB

  k_wcat<<<(GD * KX + GD + ES * HS + 255) / 256, 256, 0, stream>>>(
      W_ih, W_hh, b_ih, b_hh, W_e, Wc, bsum, Web);
  k_head<<<5, 320, 0, stream>>>(W_p, b_p, W_p2, b_p2, W_mu, b_mu, W_sd, b_sd, W_cr, b_cr,
                                Whead, bhead);

  for (int t = 0; t < T_; ++t) {
    unsigned short* Xcur  = (t & 1) ? Xbf1 : Xbf0;
    unsigned short* Xnext = (t & 1) ? Xbf0 : Xbf1;
    k_social<<<256, 512, 0, stream>>>(data, Web, b_e, Xcur, Whead, bhead,
                                      W_r, b_r, out, t);
    k_gemm_lstm<<<256, 512, 0, stream>>>(Xcur, Wc, bsum, cbuf, Xnext, t);
  }
  // h2(63) lives in Xnext of t=63 -> Xbf0 (t=63 odd)
  k_fin<<<512, 256, 0, stream>>>(data, W_r, b_r, Whead, bhead, Xbf0, out);
}